// Round 9
// baseline (206.653 us; speedup 1.0000x reference)
//
#include <hip/hip_runtime.h>
#include <hip/hip_bf16.h>

#define CCH 256
#define NSEQ 2048
#define BATCH 8

typedef __hip_bfloat16 bf16;
typedef short s8v __attribute__((ext_vector_type(8)));    // 8 bf16 (A/B frag)
typedef float f4v __attribute__((ext_vector_type(4)));    // 16x16 C/D frag
typedef float f16v __attribute__((ext_vector_type(16)));  // 32x32 C/D frag

struct __align__(8) bf16x4 { bf16 v[4]; };

__device__ __forceinline__ float b2f(bf16 h) { return __bfloat162float(h); }
__device__ __forceinline__ bf16 f2b(float f) { return __float2bfloat16(f); }

#define MFMA16(a, b, c) __builtin_amdgcn_mfma_f32_16x16x32_bf16((a), (b), (c), 0, 0, 0)
#define MFMA32(a, b, c) __builtin_amdgcn_mfma_f32_32x32x16_bf16((a), (b), (c), 0, 0, 0)

// ---------------------------------------------------------------------------
// prepw: repack 4 weight matrices fp32 -> bf16 FRAG-MAJOR:
//   frag(cs,f,l15)=W[cs*16+l15][f*8..+8] at flat (cs*32+f)*128 + l15*8.
// A wave's fragment load becomes 1KB contiguous. Grid 64 = 4 mats x 16 cs.
// ---------------------------------------------------------------------------
__global__ __launch_bounds__(256) void prepw_kernel(
    const float* __restrict__ wq, const float* __restrict__ wk,
    const float* __restrict__ wv, const float* __restrict__ wo,
    bf16* __restrict__ wqf, bf16* __restrict__ wkf,
    bf16* __restrict__ wvf, bf16* __restrict__ wof)
{
    __shared__ bf16 ws[16][264];
    const int mat = blockIdx.x >> 4, cs = blockIdx.x & 15;
    const int tid = threadIdx.x;
    const float* S = (mat == 0) ? wq : (mat == 1) ? wk : (mat == 2) ? wv : wo;
    bf16* D       = (mat == 0) ? wqf : (mat == 1) ? wkf : (mat == 2) ? wvf : wof;
    #pragma unroll
    for (int i = 0; i < 4; ++i) {
        int u = i * 1024 + tid * 4;
        int row = u >> 8, col = u & 255;
        float4 v4 = *(const float4*)&S[(size_t)(cs * 16 + row) * CCH + col];
        ws[row][col + 0] = f2b(v4.x); ws[row][col + 1] = f2b(v4.y);
        ws[row][col + 2] = f2b(v4.z); ws[row][col + 3] = f2b(v4.w);
    }
    __syncthreads();
    #pragma unroll
    for (int j = 0; j < 2; ++j) {
        int u = j * 256 + tid;
        int f = u >> 4, l = u & 15;
        s8v frag = *(const s8v*)&ws[l][f * 8];
        *(s8v*)&D[cs * 4096 + f * 128 + l * 8] = frag;
    }
}

// ---------------------------------------------------------------------------
// qkv v9: merged, grid (256 tiles, 2 phases) concurrent, 2 blocks/CU.
// Frag-major W loads (1KB coalesced). All outputs de-scattered via LDS repack:
//   q/k: T64 tile-major [tile][cblk=c/8][n64][8]; v: frag-major Vf.
//   phase 0: q (256c) + k (c 0..127); phase 1: v (256c) + k (c 128..255)
// ---------------------------------------------------------------------------
__global__ __launch_bounds__(256, 2) void qkv_kernel(
    const float* __restrict__ x,
    const bf16* __restrict__ Wqf, const bf16* __restrict__ Wkf,
    const bf16* __restrict__ Wvf,
    const float* __restrict__ bq, const float* __restrict__ bk,
    const float* __restrict__ bv,
    bf16* __restrict__ qTt, bf16* __restrict__ kTt, bf16* __restrict__ Vf)
{
    __shared__ bf16 xs[64][260];        // 33,280 B: staging + q/k repack
    __shared__ bf16 rv[4][256][18];     // 36,864 B: v repack (phase 1)

    const int tile = blockIdx.x;
    const int flat0 = tile * 64;
    const int phase = blockIdx.y;
    const int b = flat0 >> 11, nn = flat0 & 2047;
    const int tid = threadIdx.x;
    const int w = tid >> 6, lane = tid & 63;
    const int l15 = lane & 15, quad = lane >> 4;
    const int l31 = lane & 31, h = lane >> 5;
    const float* xb = x + (size_t)b * CCH * NSEQ;

    // stage + transpose x tile (fp32 [c][n] -> bf16 xs[n][c])
    #pragma unroll
    for (int i = 0; i < 16; ++i) {
        int f4i = i * 256 + tid;
        int c = f4i >> 4, nq = f4i & 15;
        float4 v4 = *(const float4*)&xb[(size_t)c * NSEQ + nn + nq * 4];
        xs[nq * 4 + 0][c] = f2b(v4.x);
        xs[nq * 4 + 1][c] = f2b(v4.y);
        xs[nq * 4 + 2][c] = f2b(v4.z);
        xs[nq * 4 + 3][c] = f2b(v4.w);
    }
    __syncthreads();                     // B1: xs staged

    s8v xf[8];
    #pragma unroll
    for (int t = 0; t < 8; ++t)
        xf[t] = *(const s8v*)&xs[w * 16 + l15][t * 32 + quad * 8];
    __syncthreads();                     // B2: xs dead -> repack buffer

    bf16* qt = qTt + (size_t)tile * 16384;
    bf16* kt = kTt + (size_t)tile * 16384;
    const s8v* Wq8 = (const s8v*)Wqf;
    const s8v* Wk8 = (const s8v*)Wkf;
    const s8v* Wv8 = (const s8v*)Wvf;

    if (phase == 0) {
        // ---- q: D[n][c], all 256 c ----
        #pragma unroll 2
        for (int cs = 0; cs < 16; ++cs) {
            f4v a = {};
            #pragma unroll
            for (int t = 0; t < 8; ++t)
                a = MFMA16(xf[t], Wq8[(cs * 32 + t * 4 + quad) * 16 + l15], a);
            int c = cs * 16 + l15;
            float bb = bq[c];
            #pragma unroll
            for (int r = 0; r < 4; ++r)
                xs[w * 16 + quad * 4 + r][c] = f2b((a[r] + bb) * 0.0625f);
        }
        __syncthreads();                 // B3: q tile in xs
        #pragma unroll
        for (int i = 0; i < 8; ++i) {
            int cblk = w * 8 + i;
            s8v row = *(const s8v*)&xs[lane][cblk * 8];
            *(s8v*)&qt[cblk * 512 + lane * 8] = row;
        }
        __syncthreads();                 // B4: q read out
        // ---- k half 1: c 0..127 ----
        #pragma unroll 2
        for (int cs = 0; cs < 8; ++cs) {
            f4v a = {};
            #pragma unroll
            for (int t = 0; t < 8; ++t)
                a = MFMA16(xf[t], Wk8[(cs * 32 + t * 4 + quad) * 16 + l15], a);
            int c = cs * 16 + l15;
            float bb = bk[c];
            #pragma unroll
            for (int r = 0; r < 4; ++r)
                xs[w * 16 + quad * 4 + r][c] = f2b(a[r] + bb);
        }
        __syncthreads();                 // B5: k-half in xs
        #pragma unroll
        for (int i = 0; i < 4; ++i) {
            int cblk = w * 4 + i;        // 0..15
            s8v row = *(const s8v*)&xs[lane][cblk * 8];
            *(s8v*)&kt[cblk * 512 + lane * 8] = row;
        }
    } else {
        // ---- v: D[c][m16] per wave -> rv[w] ----
        #pragma unroll 2
        for (int cs = 0; cs < 16; ++cs) {
            f4v a = {};
            #pragma unroll
            for (int t = 0; t < 8; ++t)
                a = MFMA16(Wv8[(cs * 32 + t * 4 + quad) * 16 + l15], xf[t], a);
            #pragma unroll
            for (int r = 0; r < 4; ++r) {
                int c = cs * 16 + quad * 4 + r;
                rv[w][c][l15] = f2b(a[r] + bv[c]);
            }
        }
        // ---- k half 2: c 128..255 -> xs ----
        #pragma unroll 2
        for (int cs = 8; cs < 16; ++cs) {
            f4v a = {};
            #pragma unroll
            for (int t = 0; t < 8; ++t)
                a = MFMA16(xf[t], Wk8[(cs * 32 + t * 4 + quad) * 16 + l15], a);
            int c = cs * 16 + l15;
            float bb = bk[c];
            #pragma unroll
            for (int r = 0; r < 4; ++r)
                xs[w * 16 + quad * 4 + r][c - 128] = f2b(a[r] + bb);
        }
        __syncthreads();                 // B3: rv + k-half ready

        // v readout: wave w -> m-chunk (nn>>4)+w, coalesced 1KB stores
        bf16* Vfb = Vf + (size_t)b * CCH * NSEQ;
        const int mc = (nn >> 4) + w;
        #pragma unroll
        for (int cb = 0; cb < 8; ++cb) {
            s8v frag = *(const s8v*)&rv[w][cb * 32 + l31][h * 8];
            *(s8v*)&Vfb[(size_t)(mc * 8 + cb) * 512 + l31 * 16 + h * 8] = frag;
        }
        // k readout: cblk 16..31
        #pragma unroll
        for (int i = 0; i < 4; ++i) {
            int cblk = w * 4 + i;
            s8v row = *(const s8v*)&xs[lane][cblk * 8];
            *(s8v*)&kt[(16 + cblk) * 512 + lane * 8] = row;
        }
    }
}

// ---------------------------------------------------------------------------
// flash v9: WAVE-SPECIALIZED. 512-thr blocks, grid (8 b, 32 nt, 2 ms) =
// 512 blocks = 2/CU = 16 waves/CU. Waves 0-3: QK+softmax (Q frags persistent,
// K frags DIRECT from T64 global — coalesced 2-segment; no K LDS). Waves 4-7:
// PV (V frags from frag-major Vf, O accumulators). P crosses via dbuf Ps:
// ONE barrier per iteration; producer i+1 overlaps consumer i.
// No-max softmax; per-lane l; unnormalized partials + l to ws.
// ---------------------------------------------------------------------------
__global__ __launch_bounds__(512, 4) void flash_kernel(
    const bf16* __restrict__ qTt, const bf16* __restrict__ kTt,
    const bf16* __restrict__ Vf, bf16* __restrict__ Opart,
    float* __restrict__ lpart)
{
    __shared__ bf16 Ps[2][64][68];     // 17,408 B
    __shared__ float l_s[2][64];

    const int b = blockIdx.x, nt = blockIdx.y, ms = blockIdx.z;
    const int tid = threadIdx.x;
    const int W = tid >> 6, lane = tid & 63;
    const int l31 = lane & 31, h = lane >> 5;
    const int mb = ms * 16;
    const bf16* Vfb = Vf + (size_t)b * CCH * NSEQ;
    const bf16* ktb = kTt + (size_t)(b * 32 + mb) * 16384;

    if (W < 4) {
        // ================= PRODUCER: QK + softmax =================
        const int ng = W >> 1, mg = W & 1;
        s8v qf[16];
        {
            const bf16* qt = qTt + (size_t)(b * 32 + nt) * 16384;
            #pragma unroll
            for (int t = 0; t < 16; ++t)
                qf[t] = *(const s8v*)&qt[(t * 2 + h) * 512 + (ng * 32 + l31) * 8];
        }
        float lacc[16] = {};

        // QK(0) -> Ps[0]
        {
            const bf16* kt = ktb;
            f16v S = {};
            #pragma unroll
            for (int t = 0; t < 16; ++t) {
                s8v kf = *(const s8v*)&kt[(t * 2 + h) * 512 + (mg * 32 + l31) * 8];
                S = MFMA32(qf[t], kf, S);
            }
            #pragma unroll
            for (int reg = 0; reg < 16; ++reg) {
                float e = __expf(fminf(S[reg], 60.f));
                lacc[reg] += e;
                int row = (reg & 3) + 8 * (reg >> 2) + 4 * h;
                Ps[0][ng * 32 + row][mg * 32 + l31] = f2b(e);
            }
        }
        __syncthreads();

        for (int i = 0; i < 16; ++i) {
            if (i < 15) {
                const bf16* kt = ktb + (size_t)(i + 1) * 16384;
                f16v S = {};
                #pragma unroll
                for (int t = 0; t < 16; ++t) {
                    s8v kf = *(const s8v*)&kt[(t * 2 + h) * 512 + (mg * 32 + l31) * 8];
                    S = MFMA32(qf[t], kf, S);
                }
                const int nxt = (i + 1) & 1;
                #pragma unroll
                for (int reg = 0; reg < 16; ++reg) {
                    float e = __expf(fminf(S[reg], 60.f));
                    lacc[reg] += e;
                    int row = (reg & 3) + 8 * (reg >> 2) + 4 * h;
                    Ps[nxt][ng * 32 + row][mg * 32 + l31] = f2b(e);
                }
            }
            __syncthreads();
        }

        // l: reduce over 32 m-lanes, publish
        #pragma unroll
        for (int reg = 0; reg < 16; ++reg) {
            float s = lacc[reg];
            #pragma unroll
            for (int off = 1; off < 32; off <<= 1) s += __shfl_xor(s, off);
            lacc[reg] = s;
        }
        if (l31 == 0) {
            #pragma unroll
            for (int reg = 0; reg < 16; ++reg) {
                int row = (reg & 3) + 8 * (reg >> 2) + 4 * h;
                l_s[mg][ng * 32 + row] = lacc[reg];
            }
        }
    } else {
        // ================= CONSUMER: PV =================
        const int ct = W - 4;            // c-quarter: rows ct*64..+63
        f16v O[2][2] = {};               // [cr][g2]
        __syncthreads();                 // match producer prologue barrier

        for (int i = 0; i < 16; ++i) {
            const int cur = i & 1;
            s8v vf[2][4];
            #pragma unroll
            for (int ks = 0; ks < 4; ++ks) {
                int mc = (mb + i) * 4 + ks;
                #pragma unroll
                for (int cr = 0; cr < 2; ++cr)
                    vf[cr][ks] = *(const s8v*)&Vfb[
                        (size_t)(mc * 8 + ct * 2 + cr) * 512 + l31 * 16 + h * 8];
            }
            #pragma unroll
            for (int ks = 0; ks < 4; ++ks) {
                s8v pf0 = *(const s8v*)&Ps[cur][l31][ks * 16 + h * 8];
                s8v pf1 = *(const s8v*)&Ps[cur][32 + l31][ks * 16 + h * 8];
                O[0][0] = MFMA32(vf[0][ks], pf0, O[0][0]);
                O[0][1] = MFMA32(vf[0][ks], pf1, O[0][1]);
                O[1][0] = MFMA32(vf[1][ks], pf0, O[1][0]);
                O[1][1] = MFMA32(vf[1][ks], pf1, O[1][1]);
            }
            __syncthreads();
        }

        // O partials -> ws (unnormalized), layout [n][c] bf16
        const size_t pb = (size_t)(b * 32 + nt) * 2 + ms;
        bf16* Ob = Opart + pb * 16384;
        #pragma unroll
        for (int cr = 0; cr < 2; ++cr)
            #pragma unroll
            for (int g2 = 0; g2 < 2; ++g2) {
                int n = g2 * 32 + l31;
                #pragma unroll
                for (int q2 = 0; q2 < 4; ++q2) {
                    bf16x4 pk;
                    #pragma unroll
                    for (int j = 0; j < 4; ++j) pk.v[j] = f2b(O[cr][g2][q2 * 4 + j]);
                    int c = ct * 64 + cr * 32 + q2 * 8 + 4 * h;
                    *(bf16x4*)&Ob[(size_t)n * 256 + c] = pk;
                }
            }
    }
    __syncthreads();
    const size_t pb = (size_t)(b * 32 + nt) * 2 + ms;
    if (tid < 64) lpart[pb * 64 + tid] = l_s[0][tid] + l_s[1][tid];
}

// ---------------------------------------------------------------------------
// outproj v5: fused reduce + frag-major Wo. Grid (256 n-tiles, 2 c-halves).
// ---------------------------------------------------------------------------
__global__ __launch_bounds__(256, 2) void outproj_kernel(
    const bf16* __restrict__ Opart, const float* __restrict__ lpart,
    const bf16* __restrict__ Wof, const float* __restrict__ bo,
    const float* __restrict__ x, float* __restrict__ out)
{
    __shared__ bf16 avs[64][260];
    __shared__ float ils[64];

    const int bx = blockIdx.x;
    const int flat0 = bx * 64;
    const int c0 = blockIdx.y * 128;
    const int tid = threadIdx.x;
    const int w = tid >> 6, lane = tid & 63;
    const int l15 = lane & 15, quad = lane >> 4;

    if (tid < 64)
        ils[tid] = 1.f / (lpart[(size_t)(bx * 2) * 64 + tid]
                        + lpart[(size_t)(bx * 2 + 1) * 64 + tid]);
    __syncthreads();

    const bf16x4* O0 = (const bf16x4*)(Opart + (size_t)(bx * 2) * 16384);
    const bf16x4* O1 = O0 + 4096;
    #pragma unroll
    for (int i = 0; i < 16; ++i) {
        int u = i * 256 + tid;
        int n = u >> 6;
        bf16x4 a = O0[u], bb = O1[u];
        float il = ils[n];
        bf16x4 o;
        #pragma unroll
        for (int t = 0; t < 4; ++t)
            o.v[t] = f2b((b2f(a.v[t]) + b2f(bb.v[t])) * il);
        *(bf16x4*)&avs[n][(u & 63) * 4] = o;
    }
    __syncthreads();

    const int bidx = flat0 >> 11, nn = flat0 & 2047;
    const size_t base = (size_t)bidx * CCH * NSEQ;
    const s8v* Wo8 = (const s8v*)Wof;

    for (int g = 0; g < 2; ++g) {
        const int cg = c0 + g * 64 + w * 16;
        const int cs = cg >> 4;
        s8v af[8];
        #pragma unroll
        for (int t = 0; t < 8; ++t)
            af[t] = Wo8[(cs * 32 + t * 4 + quad) * 16 + l15];
        f4v O[4] = {};
        #pragma unroll
        for (int nt = 0; nt < 4; ++nt)
            #pragma unroll
            for (int t = 0; t < 8; ++t) {
                s8v br = *(const s8v*)&avs[nt * 16 + l15][t * 32 + quad * 8];
                O[nt] = MFMA16(af[t], br, O[nt]);
            }
        #pragma unroll
        for (int r = 0; r < 4; ++r) {
            int c = cg + quad * 4 + r;
            float bb = bo[c];
            #pragma unroll
            for (int nt = 0; nt < 4; ++nt) {
                size_t idx = base + (size_t)c * NSEQ + nn + nt * 16 + l15;
                out[idx] = O[nt][r] + bb + x[idx];
            }
        }
    }
}

// ---------------------------------------------------------------------------
extern "C" void kernel_launch(void* const* d_in, const int* in_sizes, int n_in,
                              void* d_out, int out_size, void* d_ws, size_t ws_size,
                              hipStream_t stream) {
    (void)in_sizes; (void)n_in; (void)out_size; (void)ws_size;
    const float* x  = (const float*)d_in[0];
    const float* wq = (const float*)d_in[1];
    const float* bq = (const float*)d_in[2];
    const float* wk = (const float*)d_in[3];
    const float* bk = (const float*)d_in[4];
    const float* wv = (const float*)d_in[5];
    const float* bv = (const float*)d_in[6];
    const float* wo = (const float*)d_in[7];
    const float* bo = (const float*)d_in[8];
    float* out = (float*)d_out;

    const size_t T = (size_t)BATCH * CCH * NSEQ;   // 4,194,304
    bf16* qTt  = (bf16*)d_ws;          // T64 tile-major
    bf16* kTt  = qTt + T;
    bf16* Vf   = kTt + T;              // frag-major [b][mc][cb][c32][h][8]
    bf16* wqf  = Vf + T;               // frag-major weights
    bf16* wkf  = wqf + 65536;
    bf16* wvf  = wkf + 65536;
    bf16* wof  = wvf + 65536;
    float* lpart = (float*)(wof + 65536);        // 512 * 64 f32
    bf16* Opart  = (bf16*)(lpart + 32768);       // 512 * 16384 bf16

    prepw_kernel<<<64, 256, 0, stream>>>(wq, wk, wv, wo, wqf, wkf, wvf, wof);
    qkv_kernel<<<dim3(256, 2), 256, 0, stream>>>(
        x, wqf, wkf, wvf, bq, bk, bv, qTt, kTt, Vf);
    flash_kernel<<<dim3(8, 32, 2), 512, 0, stream>>>(qTt, kTt, Vf, Opart, lpart);
    outproj_kernel<<<dim3(256, 2), 256, 0, stream>>>(Opart, lpart, wof, bo, x, out);
}